// Round 7
// baseline (540.152 us; speedup 1.0000x reference)
//
#include <hip/hip_runtime.h>
#include <float.h>
#include <math.h>

// Problem constants
#define D_REAL 2331   // 259 channels * 3*3 patch
#define D_PAD  2336   // bf16 matrix row length
#define DQ     2304   // fp8 matrix row length (resp dims only; 18*128)
#define N_REAL 7225   // 85*85 patches
#define N_PAD  7296   // 57*128
#define JTILES 57
#define ITILES 57
#define STILES 15     // ceil(57/4) supertile grid per dim

typedef __attribute__((ext_vector_type(8))) short bf16x8_t;  // 8 bf16 = 4 VGPRs
typedef __attribute__((ext_vector_type(4))) float f32x4_t;   // 16x16 MFMA C/D
typedef __attribute__((ext_vector_type(8))) int   v8i_t;     // MX A/B operand
typedef __attribute__((ext_vector_type(4))) int   v4i_t;

__device__ __forceinline__ unsigned short f2bf(float x) {
    union { float f; unsigned int u; } v; v.f = x;
    unsigned int r = v.u + 0x7FFFu + ((v.u >> 16) & 1u);   // RNE
    return (unsigned short)(r >> 16);
}
__device__ __forceinline__ float bflo(unsigned int u) {
    union { unsigned int x; float f; } v; v.x = u << 16; return v.f;
}
__device__ __forceinline__ float bfhi(unsigned int u) {
    union { unsigned int x; float f; } v; v.x = u & 0xFFFF0000u; return v.f;
}

#define GLOAD_LDS16(g, l) __builtin_amdgcn_global_load_lds( \
    (const __attribute__((address_space(1))) void*)(g),     \
    (__attribute__((address_space(3))) void*)(l), 16, 0, 0)

// ---------------------------------------------------------------------------
// Fused build: resp part -> bf16 Pb[n][0..2304) AND fp8 Pq[n][0..2304);
// map part -> bf16 Pb[n][2304..2336) only (50 * avgpool4 + zero pad).
__global__ __launch_bounds__(256) void build_all(
        const float* __restrict__ respS, const float* __restrict__ respI,
        const float* __restrict__ mapS,  const float* __restrict__ mapI,
        unsigned short* __restrict__ PbS, unsigned short* __restrict__ PbI,
        unsigned char* __restrict__ PqS, unsigned char* __restrict__ PqI) {
    const int mat = blockIdx.y;
    unsigned short* Pb = mat ? PbI : PbS;
    const int bx = blockIdx.x;
    if (bx < 6120) {
        const float* resp = mat ? respI : respS;
        unsigned char* Pq = mat ? PqI : PqS;
        __shared__ float slab[5 * 768];        // [cc][rr][col], 15 KB max
        const int u  = bx / 72;                // 0..84
        const int d0 = (bx - u * 72) * 32;     // 0..2272
        const int c0 = d0 / 9;
        const int cN = (d0 + 31) / 9 - c0 + 1; // <= 5
        const int total4 = cN * 192;           // float4 count (768/4 per cc)
        for (int idx = threadIdx.x; idx < total4; idx += 256) {
            int cc = idx / 192;
            int rem = idx - cc * 192;          // float4 index within cc
            *(float4*)&slab[cc * 768 + rem * 4] =
                *(const float4*)&resp[(((size_t)(c0 + cc)) << 16)
                                      + ((size_t)(3 * u) << 8) + rem * 4];
        }
        __syncthreads();
        const int dl16 = threadIdx.x & 15;     // d-pair index
        const int de = d0 + 2 * dl16, dq = de + 1;
        const int ce = de / 9, re = de - ce * 9, pe = re / 3, qe = re - pe * 3;
        const int co = dq / 9, ro = dq - co * 9, po = ro / 3, qo = ro - po * 3;
        const int base_e = (ce - c0) * 768 + pe * 256 + qe;
        const int base_o = (co - c0) * 768 + po * 256 + qo;
        const int v0 = threadIdx.x >> 4;       // 0..15
        for (int v = v0; v < 85; v += 16) {
            float x0 = slab[base_e + 3 * v];
            float x1 = slab[base_o + 3 * v];
            size_t row = (size_t)(u * 85 + v);
            *(unsigned int*)&Pb[row * D_PAD + de] =
                (unsigned int)f2bf(x0) | ((unsigned int)f2bf(x1) << 16);
            int pk = __builtin_amdgcn_cvt_pk_fp8_f32(x0, x1, 0, false);
            *(unsigned short*)&Pq[row * DQ + de] = (unsigned short)pk;
        }
    } else {
        const float* map = mat ? mapI : mapS;
        int t = (bx - 6120) * 256 + threadIdx.x;
        int n = t >> 5, dm = t & 31;
        if (n >= N_REAL) return;
        float val = 0.f;
        if (dm < 27) {
            int u = n / 85, v = n - u * 85;
            int ch = dm / 9, r9 = dm - ch * 9, p = r9 / 3, q = r9 - p * 3;
            const float* mp = map + ((size_t)ch << 20)
                                  + ((size_t)((3 * u + p) * 4) << 10)
                                  + (size_t)((3 * v + q) * 4);
            float s = 0.f;
            #pragma unroll
            for (int a = 0; a < 4; a++) {      // 16B-aligned float4 rows
                float4 r = *(const float4*)(mp + a * 1024);
                s += (r.x + r.y) + (r.z + r.w);
            }
            val = 3.125f * s;                  // 50 * (1/16)
        }
        Pb[(size_t)n * D_PAD + 2304 + dm] = f2bf(val);
    }
}

// ---------------------------------------------------------------------------
// sinv[n] = 1/||S[:,n]|| (bf16 matrix).
__global__ __launch_bounds__(256) void col_norms(const unsigned short* __restrict__ Sb,
                                                 float* __restrict__ sinv) {
    int n = blockIdx.x * 4 + (threadIdx.x >> 6);
    int lane = threadIdx.x & 63;
    const uint4* sp = (const uint4*)(Sb + (size_t)n * D_PAD);
    float s = 0.f;
    for (int k = lane; k < D_PAD / 8; k += 64) {
        uint4 a = sp[k];
        float x0 = bflo(a.x), x1 = bfhi(a.x), x2 = bflo(a.y), x3 = bfhi(a.y);
        float x4 = bflo(a.z), x5 = bfhi(a.z), x6 = bflo(a.w), x7 = bfhi(a.w);
        s = fmaf(x0, x0, s); s = fmaf(x1, x1, s);
        s = fmaf(x2, x2, s); s = fmaf(x3, x3, s);
        s = fmaf(x4, x4, s); s = fmaf(x5, x5, s);
        s = fmaf(x6, x6, s); s = fmaf(x7, x7, s);
    }
    #pragma unroll
    for (int off = 32; off > 0; off >>= 1) s += __shfl_xor(s, off);
    if (lane == 0) sinv[n] = (n < N_REAL) ? rsqrtf(s) : 0.f;
}

// ---------------------------------------------------------------------------
// MX-fp8 GEMM + fused argmax. R0 skeleton, but A operand DIRECT global->reg
// (AITER-flatmm pattern): pipe accounting showed the old kernel's LDS pipe
// ~58% busy (73us reads + 24us writes + 24us conflicts of a 210us kernel) --
// the dominant pipe. A-direct halves LDS reads AND writes (B-only staging,
// 32KB LDS) at the cost of 2x A-panel L2 traffic (~14us of L2 -- cheap).
// A frags prefetch one K-tile ahead into a second reg set (A0/A1 ping-pong,
// compile-time indices); the existing __syncthreads vmcnt(0) drain orders
// them. K split: 18 x (16x16x128 f8f6f4, unit scales) + 1 bf16 16x16x32
// tail over the 50x-weighted map dims. No setprio (R5: -17us regression).
__global__ __launch_bounds__(256, 2) void gemm_argmax(
        const unsigned char* __restrict__ Sq, const unsigned char* __restrict__ Iq,
        const unsigned short* __restrict__ Sb, const unsigned short* __restrict__ Ib,
        const float* __restrict__ sinv,
        float* __restrict__ pval, int* __restrict__ pidx) {
    const int lb = blockIdx.x;
    const int sup = lb >> 4, win = lb & 15;
    const int it4 = (sup / STILES) * 4 + (win & 3);
    const int jt4 = (sup % STILES) * 4 + (win >> 2);
    if (it4 >= ITILES || jt4 >= JTILES) return;   // uniform: no barrier executed
    const int i0 = it4 * 128, j0 = jt4 * 128;

    __shared__ __align__(16) unsigned char Bf[2][128][128];   // 32 KB (B only)
    const int tid = threadIdx.x;
    const int L = tid & 63, w = tid >> 6;
    const int m = L & 15, q = L >> 4;
    const int wi = (w >> 1) * 64, wj = (w & 1) * 64;

    f32x4_t acc[4][4];
    #pragma unroll
    for (int a = 0; a < 4; a++)
        #pragma unroll
        for (int b = 0; b < 4; b++) acc[a][b] = (f32x4_t){0.f, 0.f, 0.f, 0.f};

    // B staging: lane L -> LDS row rl = L>>3 (128B rows), chunk pos L&7;
    // global 16B chunk ck = (L&7) ^ (rl&7)  (XOR involution, spreads banks).
    const int rl = L >> 3;
    const int ck = (L & 7) ^ rl;
    const unsigned char* gqb = Iq + (size_t)(j0 + w * 32 + rl) * DQ + (ck << 4);

    // read-side swizzled 16B-chunk byte offsets (row r: stored = c ^ (r&7); r&7 == m&7)
    const int clo = ((((q << 1))     ^ (m & 7)) << 4);
    const int chi = ((((q << 1) | 1) ^ (m & 7)) << 4);

    // A direct: lane (m,q) of wave w needs A[i0+wi+mi*16+m][kt*128+32q .. +32)
    // (same logical bytes the old LDS path delivered). 4 per-lane base ptrs.
    const unsigned char* gA[4];
    #pragma unroll
    for (int mi = 0; mi < 4; mi++)
        gA[mi] = Sq + (size_t)(i0 + wi + mi * 16 + m) * DQ + (q << 5);

    // bf16 tail staging, overlaid on Bf[0] (At rows 0-63, Bt rows 64-127)
    unsigned short (*At)[32] = (unsigned short(*)[32])&Bf[0][0][0];
    unsigned short (*Bt)[32] = (unsigned short(*)[32])&Bf[0][64][0];
    const int rl2 = L >> 2;
    const int ck2 = (L & 3) ^ ((rl2 >> 1) & 3);
    const unsigned short* gta = Sb + (size_t)(i0 + w * 32 + rl2) * D_PAD + 2304 + (ck2 << 3);
    const unsigned short* gtb = Ib + (size_t)(j0 + w * 32 + rl2) * D_PAD + 2304 + (ck2 << 3);
    const int cht = (q ^ ((m >> 1) & 3)) << 3;   // tail read chunk (shorts)

    v4i_t A0[8], A1[8];   // K-tile A fragments, compile-time indexed only

#define LOADA(Ar) {                                           \
    _Pragma("unroll")                                         \
    for (int mi = 0; mi < 4; mi++) {                          \
        Ar[2 * mi]     = *(const v4i_t*)(gA[mi]);             \
        Ar[2 * mi + 1] = *(const v4i_t*)(gA[mi] + 16);        \
        gA[mi] += 128;                                        \
    } }

#define PREFETCH_B(buf) {                                     \
    GLOAD_LDS16(gqb,             &Bf[buf][w * 32     ][0]);   \
    GLOAD_LDS16(gqb +  8 * DQ,   &Bf[buf][w * 32 +  8][0]);   \
    GLOAD_LDS16(gqb + 16 * DQ,   &Bf[buf][w * 32 + 16][0]);   \
    GLOAD_LDS16(gqb + 24 * DQ,   &Bf[buf][w * 32 + 24][0]);   \
    gqb += 128; }

#define COMPUTE_Q(buf, Ar) {                                               \
    v8i_t bq[4];                                                           \
    _Pragma("unroll")                                                      \
    for (int nj = 0; nj < 4; nj++) {                                       \
        v4i_t lo = *(const v4i_t*)&Bf[buf][wj + nj * 16 + m][clo];         \
        v4i_t hi = *(const v4i_t*)&Bf[buf][wj + nj * 16 + m][chi];         \
        bq[nj] = __builtin_shufflevector(lo, hi, 0, 1, 2, 3, 4, 5, 6, 7);  \
    }                                                                      \
    _Pragma("unroll")                                                      \
    for (int mi = 0; mi < 4; mi++) {                                       \
        v8i_t aq = __builtin_shufflevector(Ar[2 * mi], Ar[2 * mi + 1],     \
                                           0, 1, 2, 3, 4, 5, 6, 7);        \
        _Pragma("unroll")                                                  \
        for (int nj = 0; nj < 4; nj++)                                     \
            acc[mi][nj] = __builtin_amdgcn_mfma_scale_f32_16x16x128_f8f6f4(\
                aq, bq[nj], acc[mi][nj], 0, 0, 0, 0x7F, 0, 0x7F);          \
    } }

    LOADA(A0)                                  // tile 0 A -> regs
    PREFETCH_B(0)                              // tile 0 B -> LDS buf 0
    for (int p = 0; p < 8; p++) {              // tiles 0..15
        __syncthreads();
        LOADA(A1)                              // tile 2p+1
        PREFETCH_B(1)
        __builtin_amdgcn_sched_barrier(0);
        COMPUTE_Q(0, A0)                       // tile 2p
        __syncthreads();
        LOADA(A0)                              // tile 2p+2
        PREFETCH_B(0)
        __builtin_amdgcn_sched_barrier(0);
        COMPUTE_Q(1, A1)                       // tile 2p+1
    }
    __syncthreads();
    LOADA(A1)                                  // tile 17
    PREFETCH_B(1)
    __builtin_amdgcn_sched_barrier(0);
    COMPUTE_Q(0, A0)                           // tile 16
    __syncthreads();
    {                                          // bf16 map-dim tail -> Bf[0] overlay
        GLOAD_LDS16(gta,                      &At[w * 32][0]);
        GLOAD_LDS16(gta + (size_t)16 * D_PAD, &At[w * 32 + 16][0]);
        GLOAD_LDS16(gtb,                      &Bt[w * 32][0]);
        GLOAD_LDS16(gtb + (size_t)16 * D_PAD, &Bt[w * 32 + 16][0]);
    }
    __builtin_amdgcn_sched_barrier(0);
    COMPUTE_Q(1, A1)                           // tile 17 (reads Bf[1] only)
    __syncthreads();                           // tail tiles ready
    {
        bf16x8_t af[4], bfr[4];
        #pragma unroll
        for (int mi = 0; mi < 4; mi++)
            af[mi] = *(const bf16x8_t*)&At[wi + mi * 16 + m][cht];
        #pragma unroll
        for (int nj = 0; nj < 4; nj++)
            bfr[nj] = *(const bf16x8_t*)&Bt[wj + nj * 16 + m][cht];
        #pragma unroll
        for (int mi = 0; mi < 4; mi++)
            #pragma unroll
            for (int nj = 0; nj < 4; nj++)
                acc[mi][nj] = __builtin_amdgcn_mfma_f32_16x16x32_bf16(
                    af[mi], bfr[nj], acc[mi][nj], 0, 0, 0);
    }
#undef LOADA
#undef PREFETCH_B
#undef COMPUTE_Q

    // Epilogue. C/D layout: col = m (j-dir), row = q*4 + reg (i-dir).
    float sjv[4];
    #pragma unroll
    for (int nj = 0; nj < 4; nj++) sjv[nj] = sinv[j0 + wj + nj * 16 + m];
    #pragma unroll
    for (int mi = 0; mi < 4; mi++) {
        #pragma unroll
        for (int r = 0; r < 4; r++) {
            float best = -INFINITY; int bidx = 0x7fffffff;
            #pragma unroll
            for (int nj = 0; nj < 4; nj++) {   // j ascending -> '>' keeps smallest
                int j = j0 + wj + nj * 16 + m;
                float v = (j < N_REAL) ? acc[mi][nj][r] * sjv[nj] : -INFINITY;
                if (v > best) { best = v; bidx = j; }
            }
            #pragma unroll
            for (int off = 1; off < 16; off <<= 1) {
                float ov = __shfl_xor(best, off);
                int   oi = __shfl_xor(bidx, off);
                if (ov > best || (ov == best && oi < bidx)) { best = ov; bidx = oi; }
            }
            if (m == 0) {
                int i = i0 + wi + mi * 16 + q * 4 + r;
                pval[(size_t)jt4 * N_PAD + i] = best;
                pidx[(size_t)jt4 * N_PAD + i] = bidx;
            }
        }
    }
}

// ---------------------------------------------------------------------------
// Fused merge + loss. Per-row partial store (no same-address atomics).
__global__ __launch_bounds__(256) void loss_kernel(
        const unsigned short* __restrict__ Ib, const unsigned short* __restrict__ Sb,
        const float* __restrict__ pval, const int* __restrict__ pidx,
        double* __restrict__ partial) {
    __shared__ float wsum[4];
    __shared__ int sjn;
    const int n = blockIdx.x;
    if (threadIdx.x < 64) {                    // wave 0: merge 57 partials
        float v = -INFINITY; int id = 0x7fffffff;
        if (threadIdx.x < JTILES) {
            v  = pval[(size_t)threadIdx.x * N_PAD + n];
            id = pidx[(size_t)threadIdx.x * N_PAD + n];
        }
        #pragma unroll
        for (int off = 32; off > 0; off >>= 1) {
            float ov = __shfl_xor(v, off);
            int   oi = __shfl_xor(id, off);
            if (ov > v || (ov == v && oi < id)) { v = ov; id = oi; }
        }
        if (threadIdx.x == 0) sjn = id;
    }
    __syncthreads();
    const int jn = sjn;
    const uint4* ip = (const uint4*)(Ib + (size_t)n  * D_PAD);
    const uint4* sp = (const uint4*)(Sb + (size_t)jn * D_PAD);
    float s = 0.f;
    for (int k = threadIdx.x; k < D_PAD / 8; k += 256) {
        uint4 a = ip[k], b = sp[k];
        float d0 = bflo(a.x) - bflo(b.x), d1 = bfhi(a.x) - bfhi(b.x);
        float d2 = bflo(a.y) - bflo(b.y), d3 = bfhi(a.y) - bfhi(b.y);
        float d4 = bflo(a.z) - bflo(b.z), d5 = bfhi(a.z) - bfhi(b.z);
        float d6 = bflo(a.w) - bflo(b.w), d7 = bfhi(a.w) - bfhi(b.w);
        s = fmaf(d0, d0, s); s = fmaf(d1, d1, s);
        s = fmaf(d2, d2, s); s = fmaf(d3, d3, s);
        s = fmaf(d4, d4, s); s = fmaf(d5, d5, s);
        s = fmaf(d6, d6, s); s = fmaf(d7, d7, s);
    }
    #pragma unroll
    for (int off = 32; off > 0; off >>= 1) s += __shfl_xor(s, off);
    int lane = threadIdx.x & 63, wv = threadIdx.x >> 6;
    if (lane == 0) wsum[wv] = s;
    __syncthreads();
    if (threadIdx.x == 0) {
        partial[n] = (double)wsum[0] + (double)wsum[1]
                   + (double)wsum[2] + (double)wsum[3];
    }
}

// One-block tree reduction of the 7225 per-row partials.
__global__ __launch_bounds__(256) void finalize(const double* __restrict__ partial,
                                                float* __restrict__ out) {
    __shared__ double ws[4];
    double s = 0.0;
    for (int i = threadIdx.x; i < N_REAL; i += 256) s += partial[i];
    #pragma unroll
    for (int off = 32; off > 0; off >>= 1) s += __shfl_xor(s, off);
    int lane = threadIdx.x & 63, wv = threadIdx.x >> 6;
    if (lane == 0) ws[wv] = s;
    __syncthreads();
    if (threadIdx.x == 0) {
        double t = ws[0] + ws[1] + ws[2] + ws[3];
        out[0] = (float)(t / (double)((long long)D_REAL * N_REAL));
    }
}

// ---------------------------------------------------------------------------
extern "C" void kernel_launch(void* const* d_in, const int* in_sizes, int n_in,
                              void* d_out, int out_size, void* d_ws, size_t ws_size,
                              hipStream_t stream) {
    const float* style_resp = (const float*)d_in[0];
    const float* style_map  = (const float*)d_in[1];
    const float* output_map = (const float*)d_in[2];
    const float* model_resp = (const float*)d_in[3];
    float* out = (float*)d_out;

    unsigned short* Sb = (unsigned short*)d_ws;
    unsigned short* Ib = Sb + (size_t)D_PAD * N_PAD;
    unsigned char*  Sq = (unsigned char*)(Ib + (size_t)D_PAD * N_PAD);
    unsigned char*  Iq = Sq + (size_t)DQ * N_PAD;
    float* sinv     = (float*)(Iq + (size_t)DQ * N_PAD);
    float* pval     = sinv + N_PAD;
    int*   pidx     = (int*)(pval + (size_t)JTILES * N_PAD);
    double* partial = (double*)(pidx + (size_t)JTILES * N_PAD);

    // resp tiles: 85*72 = 6120 blocks; map part: ceil(7225*32/256) = 904 blocks
    build_all<<<dim3(6120 + 904, 2), 256, 0, stream>>>(
        style_resp, model_resp, style_map, output_map, Sb, Ib, Sq, Iq);

    col_norms<<<N_PAD / 4, 256, 0, stream>>>(Sb, sinv);

    gemm_argmax<<<STILES * STILES * 16, 256, 0, stream>>>(Sq, Iq, Sb, Ib, sinv, pval, pidx);

    loss_kernel<<<N_REAL, 256, 0, stream>>>(Ib, Sb, pval, pidx, partial);
    finalize<<<1, 256, 0, stream>>>(partial, out);
}

// Round 8
// 411.908 us; speedup vs baseline: 1.3113x; 1.3113x over previous
//
#include <hip/hip_runtime.h>
#include <float.h>
#include <math.h>

// Problem constants
#define D_REAL 2331   // 259 channels * 3*3 patch
#define D_PAD  2336   // bf16 matrix row length
#define DQ     2304   // fp8 matrix row length (resp dims only; 18*128)
#define N_REAL 7225   // 85*85 patches
#define N_PAD  7296   // 57*128
#define JTILES 57
#define ITILES 57
#define STILES 15     // ceil(57/4) supertile grid per dim

typedef __attribute__((ext_vector_type(8))) short bf16x8_t;  // 8 bf16 = 4 VGPRs
typedef __attribute__((ext_vector_type(4))) float f32x4_t;   // 16x16 MFMA C/D
typedef __attribute__((ext_vector_type(8))) int   v8i_t;     // MX A/B operand
typedef __attribute__((ext_vector_type(4))) int   v4i_t;

__device__ __forceinline__ unsigned short f2bf(float x) {
    union { float f; unsigned int u; } v; v.f = x;
    unsigned int r = v.u + 0x7FFFu + ((v.u >> 16) & 1u);   // RNE
    return (unsigned short)(r >> 16);
}
__device__ __forceinline__ float bflo(unsigned int u) {
    union { unsigned int x; float f; } v; v.x = u << 16; return v.f;
}
__device__ __forceinline__ float bfhi(unsigned int u) {
    union { unsigned int x; float f; } v; v.x = u & 0xFFFF0000u; return v.f;
}

#define GLOAD_LDS16(g, l) __builtin_amdgcn_global_load_lds( \
    (const __attribute__((address_space(1))) void*)(g),     \
    (__attribute__((address_space(3))) void*)(l), 16, 0, 0)

// ---------------------------------------------------------------------------
// Fused build: resp part -> bf16 Pb[n][0..2304) AND fp8 Pq[n][0..2304);
// map part -> bf16 Pb[n][2304..2336) only (50 * avgpool4 + zero pad).
// STYLE fp8 (GEMM A operand) is stored MFMA-FRAGMENT-FLAT: per (i-group of
// 16 rows, K-tile of 128B) a 2KB block where byte L*32+b holds
// A[grp*16+(L&15)][kt*128+(L>>4)*32+b] -- so the GEMM's A loads are two
// fully-coalesced dwordx4 per fragment (R7's uncoalesced per-lane loads
// quadrupled FETCH_SIZE; this is the AITER-flatmm pre-shuffle fix).
// IMG fp8 (B operand) stays row-major for LDS staging.
__global__ __launch_bounds__(256) void build_all(
        const float* __restrict__ respS, const float* __restrict__ respI,
        const float* __restrict__ mapS,  const float* __restrict__ mapI,
        unsigned short* __restrict__ PbS, unsigned short* __restrict__ PbI,
        unsigned char* __restrict__ PqS, unsigned char* __restrict__ PqI) {
    const int mat = blockIdx.y;
    unsigned short* Pb = mat ? PbI : PbS;
    const int bx = blockIdx.x;
    if (bx < 6120) {
        const float* resp = mat ? respI : respS;
        unsigned char* Pq = mat ? PqI : PqS;
        __shared__ float slab[5 * 768];        // [cc][rr][col], 15 KB max
        const int u  = bx / 72;                // 0..84
        const int d0 = (bx - u * 72) * 32;     // 0..2272
        const int c0 = d0 / 9;
        const int cN = (d0 + 31) / 9 - c0 + 1; // <= 5
        const int total4 = cN * 192;           // float4 count (768/4 per cc)
        for (int idx = threadIdx.x; idx < total4; idx += 256) {
            int cc = idx / 192;
            int rem = idx - cc * 192;          // float4 index within cc
            *(float4*)&slab[cc * 768 + rem * 4] =
                *(const float4*)&resp[(((size_t)(c0 + cc)) << 16)
                                      + ((size_t)(3 * u) << 8) + rem * 4];
        }
        __syncthreads();
        const int dl16 = threadIdx.x & 15;     // d-pair index
        const int de = d0 + 2 * dl16, dq = de + 1;
        const int ce = de / 9, re = de - ce * 9, pe = re / 3, qe = re - pe * 3;
        const int co = dq / 9, ro = dq - co * 9, po = ro / 3, qo = ro - po * 3;
        const int base_e = (ce - c0) * 768 + pe * 256 + qe;
        const int base_o = (co - c0) * 768 + po * 256 + qo;
        // flat-layout invariants for this thread (style side): kt and chunk q
        // are fixed (de in [d0, d0+30], d0 multiple of 32)
        const size_t fo_d = (size_t)(((de >> 5) & 3) << 9) + (de & 31);
        const int kt = de >> 7;
        const int v0 = threadIdx.x >> 4;       // 0..15
        for (int v = v0; v < 85; v += 16) {
            float x0 = slab[base_e + 3 * v];
            float x1 = slab[base_o + 3 * v];
            size_t row = (size_t)(u * 85 + v);
            *(unsigned int*)&Pb[row * D_PAD + de] =
                (unsigned int)f2bf(x0) | ((unsigned int)f2bf(x1) << 16);
            int pk = __builtin_amdgcn_cvt_pk_fp8_f32(x0, x1, 0, false);
            if (mat) {                         // img: row-major (B staging)
                *(unsigned short*)&Pq[row * DQ + de] = (unsigned short)pk;
            } else {                           // style: fragment-flat (A direct)
                size_t fo = ((row >> 4) * 18 + kt) * 2048
                          + fo_d + (size_t)((row & 15) << 5);
                *(unsigned short*)&Pq[fo] = (unsigned short)pk;
            }
        }
    } else {
        const float* map = mat ? mapI : mapS;
        int t = (bx - 6120) * 256 + threadIdx.x;
        int n = t >> 5, dm = t & 31;
        if (n >= N_REAL) return;
        float val = 0.f;
        if (dm < 27) {
            int u = n / 85, v = n - u * 85;
            int ch = dm / 9, r9 = dm - ch * 9, p = r9 / 3, q = r9 - p * 3;
            const float* mp = map + ((size_t)ch << 20)
                                  + ((size_t)((3 * u + p) * 4) << 10)
                                  + (size_t)((3 * v + q) * 4);
            float s = 0.f;
            #pragma unroll
            for (int a = 0; a < 4; a++) {      // 16B-aligned float4 rows
                float4 r = *(const float4*)(mp + a * 1024);
                s += (r.x + r.y) + (r.z + r.w);
            }
            val = 3.125f * s;                  // 50 * (1/16)
        }
        Pb[(size_t)n * D_PAD + 2304 + dm] = f2bf(val);
    }
}

// ---------------------------------------------------------------------------
// sinv[n] = 1/||S[:,n]|| (bf16 matrix).
__global__ __launch_bounds__(256) void col_norms(const unsigned short* __restrict__ Sb,
                                                 float* __restrict__ sinv) {
    int n = blockIdx.x * 4 + (threadIdx.x >> 6);
    int lane = threadIdx.x & 63;
    const uint4* sp = (const uint4*)(Sb + (size_t)n * D_PAD);
    float s = 0.f;
    for (int k = lane; k < D_PAD / 8; k += 64) {
        uint4 a = sp[k];
        float x0 = bflo(a.x), x1 = bfhi(a.x), x2 = bflo(a.y), x3 = bfhi(a.y);
        float x4 = bflo(a.z), x5 = bfhi(a.z), x6 = bflo(a.w), x7 = bfhi(a.w);
        s = fmaf(x0, x0, s); s = fmaf(x1, x1, s);
        s = fmaf(x2, x2, s); s = fmaf(x3, x3, s);
        s = fmaf(x4, x4, s); s = fmaf(x5, x5, s);
        s = fmaf(x6, x6, s); s = fmaf(x7, x7, s);
    }
    #pragma unroll
    for (int off = 32; off > 0; off >>= 1) s += __shfl_xor(s, off);
    if (lane == 0) sinv[n] = (n < N_REAL) ? rsqrtf(s) : 0.f;
}

// ---------------------------------------------------------------------------
// MX-fp8 GEMM + fused argmax. R0 skeleton; A operand direct global->reg from
// the FRAGMENT-FLAT style matrix (two coalesced dwordx4 per fragment, 2KB
// contiguous per wave per mi), one K-tile prefetch ahead (A0/A1 reg
// ping-pong). B stays LDS-staged (shared across wave columns), 32KB LDS.
// Same HBM bytes as the old global_load_lds staging; half the LDS traffic.
__global__ __launch_bounds__(256, 2) void gemm_argmax(
        const unsigned char* __restrict__ Sq, const unsigned char* __restrict__ Iq,
        const unsigned short* __restrict__ Sb, const unsigned short* __restrict__ Ib,
        const float* __restrict__ sinv,
        float* __restrict__ pval, int* __restrict__ pidx) {
    const int lb = blockIdx.x;
    const int sup = lb >> 4, win = lb & 15;
    const int it4 = (sup / STILES) * 4 + (win & 3);
    const int jt4 = (sup % STILES) * 4 + (win >> 2);
    if (it4 >= ITILES || jt4 >= JTILES) return;   // uniform: no barrier executed
    const int i0 = it4 * 128, j0 = jt4 * 128;

    __shared__ __align__(16) unsigned char Bf[2][128][128];   // 32 KB (B only)
    const int tid = threadIdx.x;
    const int L = tid & 63, w = tid >> 6;
    const int m = L & 15, q = L >> 4;
    const int wi = (w >> 1) * 64, wj = (w & 1) * 64;

    f32x4_t acc[4][4];
    #pragma unroll
    for (int a = 0; a < 4; a++)
        #pragma unroll
        for (int b = 0; b < 4; b++) acc[a][b] = (f32x4_t){0.f, 0.f, 0.f, 0.f};

    // B staging: lane L -> LDS row rl = L>>3 (128B rows), chunk pos L&7;
    // global 16B chunk ck = (L&7) ^ (rl&7)  (XOR involution, spreads banks).
    const int rl = L >> 3;
    const int ck = (L & 7) ^ rl;
    const unsigned char* gqb = Iq + (size_t)(j0 + w * 32 + rl) * DQ + (ck << 4);

    // read-side swizzled 16B-chunk byte offsets (row r: stored = c ^ (r&7); r&7 == m&7)
    const int clo = ((((q << 1))     ^ (m & 7)) << 4);
    const int chi = ((((q << 1) | 1) ^ (m & 7)) << 4);

    // A direct from fragment-flat layout: block (i_grp, kt) is 2KB; lane L
    // reads bytes [L*32, L*32+32). mi advances i_grp (+18*2048); the running
    // pointer advances 2048 per K-tile.
    const unsigned char* gAt = Sq + (size_t)((i0 + wi) >> 4) * 18 * 2048
                             + (size_t)L * 32;

    // bf16 tail staging, overlaid on Bf[0] (At rows 0-63, Bt rows 64-127)
    unsigned short (*At)[32] = (unsigned short(*)[32])&Bf[0][0][0];
    unsigned short (*Bt)[32] = (unsigned short(*)[32])&Bf[0][64][0];
    const int rl2 = L >> 2;
    const int ck2 = (L & 3) ^ ((rl2 >> 1) & 3);
    const unsigned short* gta = Sb + (size_t)(i0 + w * 32 + rl2) * D_PAD + 2304 + (ck2 << 3);
    const unsigned short* gtb = Ib + (size_t)(j0 + w * 32 + rl2) * D_PAD + 2304 + (ck2 << 3);
    const int cht = (q ^ ((m >> 1) & 3)) << 3;   // tail read chunk (shorts)

    v4i_t A0[8], A1[8];   // K-tile A fragments, compile-time indexed only

#define LOADA(Ar) {                                               \
    _Pragma("unroll")                                             \
    for (int mi = 0; mi < 4; mi++) {                              \
        Ar[2 * mi]     = *(const v4i_t*)(gAt + mi * 36864);       \
        Ar[2 * mi + 1] = *(const v4i_t*)(gAt + mi * 36864 + 16);  \
    }                                                             \
    gAt += 2048; }

#define PREFETCH_B(buf) {                                     \
    GLOAD_LDS16(gqb,             &Bf[buf][w * 32     ][0]);   \
    GLOAD_LDS16(gqb +  8 * DQ,   &Bf[buf][w * 32 +  8][0]);   \
    GLOAD_LDS16(gqb + 16 * DQ,   &Bf[buf][w * 32 + 16][0]);   \
    GLOAD_LDS16(gqb + 24 * DQ,   &Bf[buf][w * 32 + 24][0]);   \
    gqb += 128; }

#define COMPUTE_Q(buf, Ar) {                                               \
    v8i_t bq[4];                                                           \
    _Pragma("unroll")                                                      \
    for (int nj = 0; nj < 4; nj++) {                                       \
        v4i_t lo = *(const v4i_t*)&Bf[buf][wj + nj * 16 + m][clo];         \
        v4i_t hi = *(const v4i_t*)&Bf[buf][wj + nj * 16 + m][chi];         \
        bq[nj] = __builtin_shufflevector(lo, hi, 0, 1, 2, 3, 4, 5, 6, 7);  \
    }                                                                      \
    _Pragma("unroll")                                                      \
    for (int mi = 0; mi < 4; mi++) {                                       \
        v8i_t aq = __builtin_shufflevector(Ar[2 * mi], Ar[2 * mi + 1],     \
                                           0, 1, 2, 3, 4, 5, 6, 7);        \
        _Pragma("unroll")                                                  \
        for (int nj = 0; nj < 4; nj++)                                     \
            acc[mi][nj] = __builtin_amdgcn_mfma_scale_f32_16x16x128_f8f6f4(\
                aq, bq[nj], acc[mi][nj], 0, 0, 0, 0x7F, 0, 0x7F);          \
    } }

    LOADA(A0)                                  // tile 0 A -> regs
    PREFETCH_B(0)                              // tile 0 B -> LDS buf 0
    for (int p = 0; p < 8; p++) {              // tiles 0..15
        __syncthreads();
        LOADA(A1)                              // tile 2p+1
        PREFETCH_B(1)
        __builtin_amdgcn_sched_barrier(0);
        COMPUTE_Q(0, A0)                       // tile 2p
        __syncthreads();
        LOADA(A0)                              // tile 2p+2
        PREFETCH_B(0)
        __builtin_amdgcn_sched_barrier(0);
        COMPUTE_Q(1, A1)                       // tile 2p+1
    }
    __syncthreads();
    LOADA(A1)                                  // tile 17
    PREFETCH_B(1)
    __builtin_amdgcn_sched_barrier(0);
    COMPUTE_Q(0, A0)                           // tile 16
    __syncthreads();
    {                                          // bf16 map-dim tail -> Bf[0] overlay
        GLOAD_LDS16(gta,                      &At[w * 32][0]);
        GLOAD_LDS16(gta + (size_t)16 * D_PAD, &At[w * 32 + 16][0]);
        GLOAD_LDS16(gtb,                      &Bt[w * 32][0]);
        GLOAD_LDS16(gtb + (size_t)16 * D_PAD, &Bt[w * 32 + 16][0]);
    }
    __builtin_amdgcn_sched_barrier(0);
    COMPUTE_Q(1, A1)                           // tile 17 (reads Bf[1] only)
    __syncthreads();                           // tail tiles ready
    {
        bf16x8_t af[4], bfr[4];
        #pragma unroll
        for (int mi = 0; mi < 4; mi++)
            af[mi] = *(const bf16x8_t*)&At[wi + mi * 16 + m][cht];
        #pragma unroll
        for (int nj = 0; nj < 4; nj++)
            bfr[nj] = *(const bf16x8_t*)&Bt[wj + nj * 16 + m][cht];
        #pragma unroll
        for (int mi = 0; mi < 4; mi++)
            #pragma unroll
            for (int nj = 0; nj < 4; nj++)
                acc[mi][nj] = __builtin_amdgcn_mfma_f32_16x16x32_bf16(
                    af[mi], bfr[nj], acc[mi][nj], 0, 0, 0);
    }
#undef LOADA
#undef PREFETCH_B
#undef COMPUTE_Q

    // Epilogue. C/D layout: col = m (j-dir), row = q*4 + reg (i-dir).
    float sjv[4];
    #pragma unroll
    for (int nj = 0; nj < 4; nj++) sjv[nj] = sinv[j0 + wj + nj * 16 + m];
    #pragma unroll
    for (int mi = 0; mi < 4; mi++) {
        #pragma unroll
        for (int r = 0; r < 4; r++) {
            float best = -INFINITY; int bidx = 0x7fffffff;
            #pragma unroll
            for (int nj = 0; nj < 4; nj++) {   // j ascending -> '>' keeps smallest
                int j = j0 + wj + nj * 16 + m;
                float v = (j < N_REAL) ? acc[mi][nj][r] * sjv[nj] : -INFINITY;
                if (v > best) { best = v; bidx = j; }
            }
            #pragma unroll
            for (int off = 1; off < 16; off <<= 1) {
                float ov = __shfl_xor(best, off);
                int   oi = __shfl_xor(bidx, off);
                if (ov > best || (ov == best && oi < bidx)) { best = ov; bidx = oi; }
            }
            if (m == 0) {
                int i = i0 + wi + mi * 16 + q * 4 + r;
                pval[(size_t)jt4 * N_PAD + i] = best;
                pidx[(size_t)jt4 * N_PAD + i] = bidx;
            }
        }
    }
}

// ---------------------------------------------------------------------------
// Fused merge + loss. Per-row partial store (no same-address atomics).
__global__ __launch_bounds__(256) void loss_kernel(
        const unsigned short* __restrict__ Ib, const unsigned short* __restrict__ Sb,
        const float* __restrict__ pval, const int* __restrict__ pidx,
        double* __restrict__ partial) {
    __shared__ float wsum[4];
    __shared__ int sjn;
    const int n = blockIdx.x;
    if (threadIdx.x < 64) {                    // wave 0: merge 57 partials
        float v = -INFINITY; int id = 0x7fffffff;
        if (threadIdx.x < JTILES) {
            v  = pval[(size_t)threadIdx.x * N_PAD + n];
            id = pidx[(size_t)threadIdx.x * N_PAD + n];
        }
        #pragma unroll
        for (int off = 32; off > 0; off >>= 1) {
            float ov = __shfl_xor(v, off);
            int   oi = __shfl_xor(id, off);
            if (ov > v || (ov == v && oi < id)) { v = ov; id = oi; }
        }
        if (threadIdx.x == 0) sjn = id;
    }
    __syncthreads();
    const int jn = sjn;
    const uint4* ip = (const uint4*)(Ib + (size_t)n  * D_PAD);
    const uint4* sp = (const uint4*)(Sb + (size_t)jn * D_PAD);
    float s = 0.f;
    for (int k = threadIdx.x; k < D_PAD / 8; k += 256) {
        uint4 a = ip[k], b = sp[k];
        float d0 = bflo(a.x) - bflo(b.x), d1 = bfhi(a.x) - bfhi(b.x);
        float d2 = bflo(a.y) - bflo(b.y), d3 = bfhi(a.y) - bfhi(b.y);
        float d4 = bflo(a.z) - bflo(b.z), d5 = bfhi(a.z) - bfhi(b.z);
        float d6 = bflo(a.w) - bflo(b.w), d7 = bfhi(a.w) - bfhi(b.w);
        s = fmaf(d0, d0, s); s = fmaf(d1, d1, s);
        s = fmaf(d2, d2, s); s = fmaf(d3, d3, s);
        s = fmaf(d4, d4, s); s = fmaf(d5, d5, s);
        s = fmaf(d6, d6, s); s = fmaf(d7, d7, s);
    }
    #pragma unroll
    for (int off = 32; off > 0; off >>= 1) s += __shfl_xor(s, off);
    int lane = threadIdx.x & 63, wv = threadIdx.x >> 6;
    if (lane == 0) wsum[wv] = s;
    __syncthreads();
    if (threadIdx.x == 0) {
        partial[n] = (double)wsum[0] + (double)wsum[1]
                   + (double)wsum[2] + (double)wsum[3];
    }
}

// One-block tree reduction of the 7225 per-row partials.
__global__ __launch_bounds__(256) void finalize(const double* __restrict__ partial,
                                                float* __restrict__ out) {
    __shared__ double ws[4];
    double s = 0.0;
    for (int i = threadIdx.x; i < N_REAL; i += 256) s += partial[i];
    #pragma unroll
    for (int off = 32; off > 0; off >>= 1) s += __shfl_xor(s, off);
    int lane = threadIdx.x & 63, wv = threadIdx.x >> 6;
    if (lane == 0) ws[wv] = s;
    __syncthreads();
    if (threadIdx.x == 0) {
        double t = ws[0] + ws[1] + ws[2] + ws[3];
        out[0] = (float)(t / (double)((long long)D_REAL * N_REAL));
    }
}

// ---------------------------------------------------------------------------
extern "C" void kernel_launch(void* const* d_in, const int* in_sizes, int n_in,
                              void* d_out, int out_size, void* d_ws, size_t ws_size,
                              hipStream_t stream) {
    const float* style_resp = (const float*)d_in[0];
    const float* style_map  = (const float*)d_in[1];
    const float* output_map = (const float*)d_in[2];
    const float* model_resp = (const float*)d_in[3];
    float* out = (float*)d_out;

    unsigned short* Sb = (unsigned short*)d_ws;
    unsigned short* Ib = Sb + (size_t)D_PAD * N_PAD;
    unsigned char*  Sq = (unsigned char*)(Ib + (size_t)D_PAD * N_PAD);  // flat A
    unsigned char*  Iq = Sq + (size_t)DQ * N_PAD;                       // row-major B
    float* sinv     = (float*)(Iq + (size_t)DQ * N_PAD);
    float* pval     = sinv + N_PAD;
    int*   pidx     = (int*)(pval + (size_t)JTILES * N_PAD);
    double* partial = (double*)(pidx + (size_t)JTILES * N_PAD);

    // resp tiles: 85*72 = 6120 blocks; map part: ceil(7225*32/256) = 904 blocks
    build_all<<<dim3(6120 + 904, 2), 256, 0, stream>>>(
        style_resp, model_resp, style_map, output_map, Sb, Ib, Sq, Iq);

    col_norms<<<N_PAD / 4, 256, 0, stream>>>(Sb, sinv);

    gemm_argmax<<<STILES * STILES * 16, 256, 0, stream>>>(Sq, Iq, Sb, Ib, sinv, pval, pidx);

    loss_kernel<<<N_REAL, 256, 0, stream>>>(Ib, Sb, pval, pidx, partial);
    finalize<<<1, 256, 0, stream>>>(partial, out);
}

// Round 9
// 407.999 us; speedup vs baseline: 1.3239x; 1.0096x over previous
//
#include <hip/hip_runtime.h>
#include <float.h>
#include <math.h>

// Problem constants
#define D_REAL 2331   // 259 channels * 3*3 patch
#define D_PAD  2336   // bf16 matrix row length
#define DQ     2304   // fp8 matrix row length (resp dims only; 18*128)
#define N_REAL 7225   // 85*85 patches
#define N_PAD  7296   // 57*128
#define JTILES 57
#define ITILES 57
#define STILES 15     // ceil(57/4) supertile grid per dim

typedef __attribute__((ext_vector_type(8))) short bf16x8_t;  // 8 bf16 = 4 VGPRs
typedef __attribute__((ext_vector_type(4))) float f32x4_t;   // 16x16 MFMA C/D
typedef __attribute__((ext_vector_type(8))) int   v8i_t;     // MX A/B operand
typedef __attribute__((ext_vector_type(4))) int   v4i_t;

__device__ __forceinline__ unsigned short f2bf(float x) {
    union { float f; unsigned int u; } v; v.f = x;
    unsigned int r = v.u + 0x7FFFu + ((v.u >> 16) & 1u);   // RNE
    return (unsigned short)(r >> 16);
}
__device__ __forceinline__ float bflo(unsigned int u) {
    union { unsigned int x; float f; } v; v.x = u << 16; return v.f;
}
__device__ __forceinline__ float bfhi(unsigned int u) {
    union { unsigned int x; float f; } v; v.x = u & 0xFFFF0000u; return v.f;
}

#define GLOAD_LDS16(g, l) __builtin_amdgcn_global_load_lds( \
    (const __attribute__((address_space(1))) void*)(g),     \
    (__attribute__((address_space(3))) void*)(l), 16, 0, 0)

// ---------------------------------------------------------------------------
// Fused build: resp part -> bf16 Pb[n][0..2304) AND fp8 Pq[n][0..2304);
// map part -> bf16 Pb[n][2304..2336) only (50 * avgpool4 + zero pad).
// STYLE fp8 (GEMM A operand) stored MFMA-FRAGMENT-FLAT (R8): per (i-group of
// 16 rows, K-tile of 128B) a 2KB block where byte L*32+b holds
// A[grp*16+(L&15)][kt*128+(L>>4)*32+b] -- GEMM A loads are coalesced dwordx4.
// IMG fp8 (B operand) stays row-major for LDS staging.
__global__ __launch_bounds__(256) void build_all(
        const float* __restrict__ respS, const float* __restrict__ respI,
        const float* __restrict__ mapS,  const float* __restrict__ mapI,
        unsigned short* __restrict__ PbS, unsigned short* __restrict__ PbI,
        unsigned char* __restrict__ PqS, unsigned char* __restrict__ PqI) {
    const int mat = blockIdx.y;
    unsigned short* Pb = mat ? PbI : PbS;
    const int bx = blockIdx.x;
    if (bx < 6120) {
        const float* resp = mat ? respI : respS;
        unsigned char* Pq = mat ? PqI : PqS;
        __shared__ float slab[5 * 768];        // [cc][rr][col], 15 KB max
        const int u  = bx / 72;                // 0..84
        const int d0 = (bx - u * 72) * 32;     // 0..2272
        const int c0 = d0 / 9;
        const int cN = (d0 + 31) / 9 - c0 + 1; // <= 5
        const int total4 = cN * 192;           // float4 count (768/4 per cc)
        for (int idx = threadIdx.x; idx < total4; idx += 256) {
            int cc = idx / 192;
            int rem = idx - cc * 192;          // float4 index within cc
            *(float4*)&slab[cc * 768 + rem * 4] =
                *(const float4*)&resp[(((size_t)(c0 + cc)) << 16)
                                      + ((size_t)(3 * u) << 8) + rem * 4];
        }
        __syncthreads();
        const int dl16 = threadIdx.x & 15;     // d-pair index
        const int de = d0 + 2 * dl16, dq = de + 1;
        const int ce = de / 9, re = de - ce * 9, pe = re / 3, qe = re - pe * 3;
        const int co = dq / 9, ro = dq - co * 9, po = ro / 3, qo = ro - po * 3;
        const int base_e = (ce - c0) * 768 + pe * 256 + qe;
        const int base_o = (co - c0) * 768 + po * 256 + qo;
        // flat-layout invariants (style side): kt and chunk q fixed per thread
        const size_t fo_d = (size_t)(((de >> 5) & 3) << 9) + (de & 31);
        const int kt = de >> 7;
        const int v0 = threadIdx.x >> 4;       // 0..15
        for (int v = v0; v < 85; v += 16) {
            float x0 = slab[base_e + 3 * v];
            float x1 = slab[base_o + 3 * v];
            size_t row = (size_t)(u * 85 + v);
            *(unsigned int*)&Pb[row * D_PAD + de] =
                (unsigned int)f2bf(x0) | ((unsigned int)f2bf(x1) << 16);
            int pk = __builtin_amdgcn_cvt_pk_fp8_f32(x0, x1, 0, false);
            if (mat) {                         // img: row-major (B staging)
                *(unsigned short*)&Pq[row * DQ + de] = (unsigned short)pk;
            } else {                           // style: fragment-flat (A direct)
                size_t fo = ((row >> 4) * 18 + kt) * 2048
                          + fo_d + (size_t)((row & 15) << 5);
                *(unsigned short*)&Pq[fo] = (unsigned short)pk;
            }
        }
    } else {
        const float* map = mat ? mapI : mapS;
        int t = (bx - 6120) * 256 + threadIdx.x;
        int n = t >> 5, dm = t & 31;
        if (n >= N_REAL) return;
        float val = 0.f;
        if (dm < 27) {
            int u = n / 85, v = n - u * 85;
            int ch = dm / 9, r9 = dm - ch * 9, p = r9 / 3, q = r9 - p * 3;
            const float* mp = map + ((size_t)ch << 20)
                                  + ((size_t)((3 * u + p) * 4) << 10)
                                  + (size_t)((3 * v + q) * 4);
            float s = 0.f;
            #pragma unroll
            for (int a = 0; a < 4; a++) {      // 16B-aligned float4 rows
                float4 r = *(const float4*)(mp + a * 1024);
                s += (r.x + r.y) + (r.z + r.w);
            }
            val = 3.125f * s;                  // 50 * (1/16)
        }
        Pb[(size_t)n * D_PAD + 2304 + dm] = f2bf(val);
    }
}

// ---------------------------------------------------------------------------
// sinv[n] = 1/||S[:,n]|| (bf16 matrix).
__global__ __launch_bounds__(256) void col_norms(const unsigned short* __restrict__ Sb,
                                                 float* __restrict__ sinv) {
    int n = blockIdx.x * 4 + (threadIdx.x >> 6);
    int lane = threadIdx.x & 63;
    const uint4* sp = (const uint4*)(Sb + (size_t)n * D_PAD);
    float s = 0.f;
    for (int k = lane; k < D_PAD / 8; k += 64) {
        uint4 a = sp[k];
        float x0 = bflo(a.x), x1 = bfhi(a.x), x2 = bflo(a.y), x3 = bfhi(a.y);
        float x4 = bflo(a.z), x5 = bfhi(a.z), x6 = bflo(a.w), x7 = bfhi(a.w);
        s = fmaf(x0, x0, s); s = fmaf(x1, x1, s);
        s = fmaf(x2, x2, s); s = fmaf(x3, x3, s);
        s = fmaf(x4, x4, s); s = fmaf(x5, x5, s);
        s = fmaf(x6, x6, s); s = fmaf(x7, x7, s);
    }
    #pragma unroll
    for (int off = 32; off > 0; off >>= 1) s += __shfl_xor(s, off);
    if (lane == 0) sinv[n] = (n < N_REAL) ? rsqrtf(s) : 0.f;
}

// ---------------------------------------------------------------------------
// MX-fp8 GEMM + fused argmax. R8 operand routing (A direct from fragment-flat
// global, B LDS-staged) + T4 COUNTED-VMCNT schedule: the old per-tile
// __syncthreads() drained vmcnt(0) ~150cy after issuing the next tile's
// loads, exposing ~600-900cy of L2/HBM latency twice per tile (the ~3500cy/
// tile gap in the R8 accounting). Now: 4-deep B ring (64KB LDS, 2 blocks/CU),
// per tile issue {A(t+1): 8 loads, B(t+2): 4 gload_lds} -> s_waitcnt
// vmcnt(16) (the exactly-16 newer loads; A(t)/B(t) are older -> landed) ->
// RAW s_barrier (no drain) -> compute. One barrier/tile. Race-freedom:
// buf[s&3] write-issue (tile s-2) is 2 barriers after its last read (s-4);
// barrier-skew <=1; gate-then-barrier makes other waves' gload_lds visible
// (m201 discipline). Epilogue: t16 gates 16 (tail staged into freed buf2),
// t17 gates 4, tail gates 0.
__global__ __launch_bounds__(256, 2) void gemm_argmax(
        const unsigned char* __restrict__ Sq, const unsigned char* __restrict__ Iq,
        const unsigned short* __restrict__ Sb, const unsigned short* __restrict__ Ib,
        const float* __restrict__ sinv,
        float* __restrict__ pval, int* __restrict__ pidx) {
    const int lb = blockIdx.x;
    const int sup = lb >> 4, win = lb & 15;
    const int it4 = (sup / STILES) * 4 + (win & 3);
    const int jt4 = (sup % STILES) * 4 + (win >> 2);
    if (it4 >= ITILES || jt4 >= JTILES) return;   // uniform: no barrier executed
    const int i0 = it4 * 128, j0 = jt4 * 128;

    __shared__ __align__(16) unsigned char Bf[4][128][128];   // 64 KB B ring
    const int tid = threadIdx.x;
    const int L = tid & 63, w = tid >> 6;
    const int m = L & 15, q = L >> 4;
    const int wi = (w >> 1) * 64, wj = (w & 1) * 64;

    f32x4_t acc[4][4];
    #pragma unroll
    for (int a = 0; a < 4; a++)
        #pragma unroll
        for (int b = 0; b < 4; b++) acc[a][b] = (f32x4_t){0.f, 0.f, 0.f, 0.f};

    // B staging: lane L -> LDS row rl = L>>3 (128B rows), chunk pos L&7;
    // global 16B chunk ck = (L&7) ^ (rl&7)  (XOR involution, spreads banks).
    const int rl = L >> 3;
    const int ck = (L & 7) ^ rl;
    const unsigned char* gqb = Iq + (size_t)(j0 + w * 32 + rl) * DQ + (ck << 4);

    // read-side swizzled 16B-chunk byte offsets (row r: stored = c ^ (r&7); r&7 == m&7)
    const int clo = ((((q << 1))     ^ (m & 7)) << 4);
    const int chi = ((((q << 1) | 1) ^ (m & 7)) << 4);

    // A direct from fragment-flat layout: block (i_grp, kt) is 2KB; lane L
    // reads bytes [L*32, L*32+32). mi advances i_grp (+18*2048); running
    // pointer advances 2048 per K-tile.
    const unsigned char* gAt = Sq + (size_t)((i0 + wi) >> 4) * 18 * 2048
                             + (size_t)L * 32;

    // bf16 tail staging, overlaid on Bf[2] (At = A-tail [128][32]sh = 8KB at
    // base, Bt = B-tail 8KB at +8KB), staged at t16 after Bf[2]'s last read (t14).
    unsigned short (*At)[32] = (unsigned short(*)[32])&Bf[2][0][0];
    unsigned short (*Bt)[32] = (unsigned short(*)[32])&Bf[2][64][0];
    const int rl2 = L >> 2;
    const int ck2 = (L & 3) ^ ((rl2 >> 1) & 3);
    const unsigned short* gta = Sb + (size_t)(i0 + w * 32 + rl2) * D_PAD + 2304 + (ck2 << 3);
    const unsigned short* gtb = Ib + (size_t)(j0 + w * 32 + rl2) * D_PAD + 2304 + (ck2 << 3);
    const int cht = (q ^ ((m >> 1) & 3)) << 3;   // tail read chunk (shorts)

    v4i_t A0[8], A1[8];   // K-tile A fragments, compile-time indexed only

#define LOADA(Ar) {                                               \
    _Pragma("unroll")                                             \
    for (int mi = 0; mi < 4; mi++) {                              \
        Ar[2 * mi]     = *(const v4i_t*)(gAt + mi * 36864);       \
        Ar[2 * mi + 1] = *(const v4i_t*)(gAt + mi * 36864 + 16);  \
    }                                                             \
    gAt += 2048; }

#define PREFETCH_B(buf) {                                     \
    GLOAD_LDS16(gqb,             &Bf[buf][w * 32     ][0]);   \
    GLOAD_LDS16(gqb +  8 * DQ,   &Bf[buf][w * 32 +  8][0]);   \
    GLOAD_LDS16(gqb + 16 * DQ,   &Bf[buf][w * 32 + 16][0]);   \
    GLOAD_LDS16(gqb + 24 * DQ,   &Bf[buf][w * 32 + 24][0]);   \
    gqb += 128; }

#define GATE(N) asm volatile("s_waitcnt vmcnt(" #N ")" ::: "memory");
#define BARRIER  __builtin_amdgcn_s_barrier(); \
                 __builtin_amdgcn_sched_barrier(0);

#define COMPUTE_Q(buf, Ar) {                                               \
    v8i_t bq[4];                                                           \
    _Pragma("unroll")                                                      \
    for (int nj = 0; nj < 4; nj++) {                                       \
        v4i_t lo = *(const v4i_t*)&Bf[buf][wj + nj * 16 + m][clo];         \
        v4i_t hi = *(const v4i_t*)&Bf[buf][wj + nj * 16 + m][chi];         \
        bq[nj] = __builtin_shufflevector(lo, hi, 0, 1, 2, 3, 4, 5, 6, 7);  \
    }                                                                      \
    _Pragma("unroll")                                                      \
    for (int mi = 0; mi < 4; mi++) {                                       \
        v8i_t aq = __builtin_shufflevector(Ar[2 * mi], Ar[2 * mi + 1],     \
                                           0, 1, 2, 3, 4, 5, 6, 7);        \
        _Pragma("unroll")                                                  \
        for (int nj = 0; nj < 4; nj++)                                     \
            acc[mi][nj] = __builtin_amdgcn_mfma_scale_f32_16x16x128_f8f6f4(\
                aq, bq[nj], acc[mi][nj], 0, 0, 0, 0x7F, 0, 0x7F);          \
    } }

    // Prologue: A(t0) + B(t0)->buf0 + B(t1)->buf1. 16 outstanding.
    LOADA(A0)
    PREFETCH_B(0)
    PREFETCH_B(1)

    // Main loop, tiles 0..15. Per tile t: issue A(t+1) + B(t+2), gate 16,
    // raw barrier, compute tile t from buf[t&3] with A[t&1].
    #pragma unroll 1
    for (int p = 0; p < 4; p++) {
        LOADA(A1) PREFETCH_B(2) GATE(16) BARRIER COMPUTE_Q(0, A0)
        LOADA(A0) PREFETCH_B(3) GATE(16) BARRIER COMPUTE_Q(1, A1)
        LOADA(A1) PREFETCH_B(0) GATE(16) BARRIER COMPUTE_Q(2, A0)
        LOADA(A0) PREFETCH_B(1) GATE(16) BARRIER COMPUTE_Q(3, A1)
    }
    // t=16: A(17) + tail-stage into buf2 (last read t14; >=2 barriers ago).
    LOADA(A1)
    {
        GLOAD_LDS16(gta,                      &At[w * 32][0]);
        GLOAD_LDS16(gta + (size_t)16 * D_PAD, &At[w * 32 + 16][0]);
        GLOAD_LDS16(gtb,                      &Bt[w * 32][0]);
        GLOAD_LDS16(gtb + (size_t)16 * D_PAD, &Bt[w * 32 + 16][0]);
    }
    GATE(16) BARRIER COMPUTE_Q(0, A0)          // tile 16 (buf0)
    // t=17: outstanding = tail(4); A17/B17 older -> landed at gate 4.
    GATE(4) BARRIER COMPUTE_Q(1, A1)           // tile 17 (buf1)
    // tail: gate 0 + barrier -> all waves' tail stages visible.
    GATE(0) BARRIER
    {
        bf16x8_t af[4], bfr[4];
        #pragma unroll
        for (int mi = 0; mi < 4; mi++)
            af[mi] = *(const bf16x8_t*)&At[wi + mi * 16 + m][cht];
        #pragma unroll
        for (int nj = 0; nj < 4; nj++)
            bfr[nj] = *(const bf16x8_t*)&Bt[wj + nj * 16 + m][cht];
        #pragma unroll
        for (int mi = 0; mi < 4; mi++)
            #pragma unroll
            for (int nj = 0; nj < 4; nj++)
                acc[mi][nj] = __builtin_amdgcn_mfma_f32_16x16x32_bf16(
                    af[mi], bfr[nj], acc[mi][nj], 0, 0, 0);
    }
#undef LOADA
#undef PREFETCH_B
#undef GATE
#undef BARRIER
#undef COMPUTE_Q

    // Epilogue. C/D layout: col = m (j-dir), row = q*4 + reg (i-dir).
    float sjv[4];
    #pragma unroll
    for (int nj = 0; nj < 4; nj++) sjv[nj] = sinv[j0 + wj + nj * 16 + m];
    #pragma unroll
    for (int mi = 0; mi < 4; mi++) {
        #pragma unroll
        for (int r = 0; r < 4; r++) {
            float best = -INFINITY; int bidx = 0x7fffffff;
            #pragma unroll
            for (int nj = 0; nj < 4; nj++) {   // j ascending -> '>' keeps smallest
                int j = j0 + wj + nj * 16 + m;
                float v = (j < N_REAL) ? acc[mi][nj][r] * sjv[nj] : -INFINITY;
                if (v > best) { best = v; bidx = j; }
            }
            #pragma unroll
            for (int off = 1; off < 16; off <<= 1) {
                float ov = __shfl_xor(best, off);
                int   oi = __shfl_xor(bidx, off);
                if (ov > best || (ov == best && oi < bidx)) { best = ov; bidx = oi; }
            }
            if (m == 0) {
                int i = i0 + wi + mi * 16 + q * 4 + r;
                pval[(size_t)jt4 * N_PAD + i] = best;
                pidx[(size_t)jt4 * N_PAD + i] = bidx;
            }
        }
    }
}

// ---------------------------------------------------------------------------
// Fused merge + loss. Per-row partial store (no same-address atomics).
__global__ __launch_bounds__(256) void loss_kernel(
        const unsigned short* __restrict__ Ib, const unsigned short* __restrict__ Sb,
        const float* __restrict__ pval, const int* __restrict__ pidx,
        double* __restrict__ partial) {
    __shared__ float wsum[4];
    __shared__ int sjn;
    const int n = blockIdx.x;
    if (threadIdx.x < 64) {                    // wave 0: merge 57 partials
        float v = -INFINITY; int id = 0x7fffffff;
        if (threadIdx.x < JTILES) {
            v  = pval[(size_t)threadIdx.x * N_PAD + n];
            id = pidx[(size_t)threadIdx.x * N_PAD + n];
        }
        #pragma unroll
        for (int off = 32; off > 0; off >>= 1) {
            float ov = __shfl_xor(v, off);
            int   oi = __shfl_xor(id, off);
            if (ov > v || (ov == v && oi < id)) { v = ov; id = oi; }
        }
        if (threadIdx.x == 0) sjn = id;
    }
    __syncthreads();
    const int jn = sjn;
    const uint4* ip = (const uint4*)(Ib + (size_t)n  * D_PAD);
    const uint4* sp = (const uint4*)(Sb + (size_t)jn * D_PAD);
    float s = 0.f;
    for (int k = threadIdx.x; k < D_PAD / 8; k += 256) {
        uint4 a = ip[k], b = sp[k];
        float d0 = bflo(a.x) - bflo(b.x), d1 = bfhi(a.x) - bfhi(b.x);
        float d2 = bflo(a.y) - bflo(b.y), d3 = bfhi(a.y) - bfhi(b.y);
        float d4 = bflo(a.z) - bflo(b.z), d5 = bfhi(a.z) - bfhi(b.z);
        float d6 = bflo(a.w) - bflo(b.w), d7 = bfhi(a.w) - bfhi(b.w);
        s = fmaf(d0, d0, s); s = fmaf(d1, d1, s);
        s = fmaf(d2, d2, s); s = fmaf(d3, d3, s);
        s = fmaf(d4, d4, s); s = fmaf(d5, d5, s);
        s = fmaf(d6, d6, s); s = fmaf(d7, d7, s);
    }
    #pragma unroll
    for (int off = 32; off > 0; off >>= 1) s += __shfl_xor(s, off);
    int lane = threadIdx.x & 63, wv = threadIdx.x >> 6;
    if (lane == 0) wsum[wv] = s;
    __syncthreads();
    if (threadIdx.x == 0) {
        partial[n] = (double)wsum[0] + (double)wsum[1]
                   + (double)wsum[2] + (double)wsum[3];
    }
}

// One-block tree reduction of the 7225 per-row partials.
__global__ __launch_bounds__(256) void finalize(const double* __restrict__ partial,
                                                float* __restrict__ out) {
    __shared__ double ws[4];
    double s = 0.0;
    for (int i = threadIdx.x; i < N_REAL; i += 256) s += partial[i];
    #pragma unroll
    for (int off = 32; off > 0; off >>= 1) s += __shfl_xor(s, off);
    int lane = threadIdx.x & 63, wv = threadIdx.x >> 6;
    if (lane == 0) ws[wv] = s;
    __syncthreads();
    if (threadIdx.x == 0) {
        double t = ws[0] + ws[1] + ws[2] + ws[3];
        out[0] = (float)(t / (double)((long long)D_REAL * N_REAL));
    }
}

// ---------------------------------------------------------------------------
extern "C" void kernel_launch(void* const* d_in, const int* in_sizes, int n_in,
                              void* d_out, int out_size, void* d_ws, size_t ws_size,
                              hipStream_t stream) {
    const float* style_resp = (const float*)d_in[0];
    const float* style_map  = (const float*)d_in[1];
    const float* output_map = (const float*)d_in[2];
    const float* model_resp = (const float*)d_in[3];
    float* out = (float*)d_out;

    unsigned short* Sb = (unsigned short*)d_ws;
    unsigned short* Ib = Sb + (size_t)D_PAD * N_PAD;
    unsigned char*  Sq = (unsigned char*)(Ib + (size_t)D_PAD * N_PAD);  // flat A
    unsigned char*  Iq = Sq + (size_t)DQ * N_PAD;                       // row-major B
    float* sinv     = (float*)(Iq + (size_t)DQ * N_PAD);
    float* pval     = sinv + N_PAD;
    int*   pidx     = (int*)(pval + (size_t)JTILES * N_PAD);
    double* partial = (double*)(pidx + (size_t)JTILES * N_PAD);

    // resp tiles: 85*72 = 6120 blocks; map part: ceil(7225*32/256) = 904 blocks
    build_all<<<dim3(6120 + 904, 2), 256, 0, stream>>>(
        style_resp, model_resp, style_map, output_map, Sb, Ib, Sq, Iq);

    col_norms<<<N_PAD / 4, 256, 0, stream>>>(Sb, sinv);

    gemm_argmax<<<STILES * STILES * 16, 256, 0, stream>>>(Sq, Iq, Sb, Ib, sinv, pval, pidx);

    loss_kernel<<<N_REAL, 256, 0, stream>>>(Ib, Sb, pval, pidx, partial);
    finalize<<<1, 256, 0, stream>>>(partial, out);
}